// Round 1
// baseline (2571.576 us; speedup 1.0000x reference)
//
#include <hip/hip_runtime.h>
#include <hip/hip_cooperative_groups.h>

namespace cg = cooperative_groups;

#define NB 32
#define NT 1024
#define ND 1024
#define NH 1024
#define G3 3072          // 3*NH
#define MROWS 32768      // NB*NT
#define HROWS 16512      // max segments with len>=2 is 16384; +padding

typedef __bf16 bf16x8 __attribute__((ext_vector_type(8)));
typedef float f32x4 __attribute__((ext_vector_type(4)));
typedef unsigned short u16x8 __attribute__((ext_vector_type(8)));

__device__ __forceinline__ float b2f(unsigned short u){
  union { unsigned int i; float f; } v; v.i = ((unsigned int)u) << 16; return v.f;
}
__device__ __forceinline__ unsigned short f2b(float f){
  union { float f; unsigned int i; } v; v.f = f;
  unsigned int r = (v.i + 0x7FFFu + ((v.i >> 16) & 1u)) >> 16;
  return (unsigned short)r;
}
__device__ __forceinline__ float sigm(float x){ return 1.0f / (1.0f + __expf(-x)); }
__device__ __forceinline__ float tanh_(float x){ return 2.0f / (1.0f + __expf(-2.0f * x)) - 1.0f; }

// ---------------- K1: convert weights fp32 -> bf16 ----------------
__global__ __launch_bounds__(256) void k_convw(const float* __restrict__ wih,
                                               const float* __restrict__ whh,
                                               unsigned short* __restrict__ wih_b,
                                               unsigned short* __restrict__ whh_b, int n){
  int i = blockIdx.x * blockDim.x + threadIdx.x;
  int stride = gridDim.x * blockDim.x;
  for (; i < n; i += stride){
    wih_b[i] = f2b(wih[i]);
    whh_b[i] = f2b(whh[i]);
  }
}

// ---------------- K2: segment build + counting sort (single block) ----------------
__global__ __launch_bounds__(1024) void k_segbuild(const int* __restrict__ seg,
    int* __restrict__ ugi, int* __restrict__ uout, int* __restrict__ ulen,
    int* __restrict__ nseg_b,
    int* __restrict__ sgi, int* __restrict__ sout, int* __restrict__ slen,
    int* __restrict__ cnt_ge, float* __restrict__ counts_out){
  __shared__ int hist[1025];
  __shared__ int offs[1025];
  int tid = threadIdx.x;
  int wave = tid >> 6, lane = tid & 63;

  // per-batch wave scan: enumerate segments (one per zero position)
  for (int b = wave; b < NB; b += 16){
    int prev = -1;   // position of previous zero (lane-uniform)
    int zc = 0;      // zeros so far
    for (int c = 0; c < 16; ++c){
      int t = c * 64 + lane;
      int v = seg[b * NT + t];
      unsigned long long mask = __ballot(v == 0);
      unsigned long long below = mask & ((1ULL << lane) - 1ULL);
      if (v == 0){
        int pz = below ? (c * 64 + (63 - __clzll((long long)below))) : prev;
        int eidx = zc + __popcll(below);
        int slot = b * NT + eidx;
        ugi[slot]  = b * NT + (pz + 1);  // Gi row of segment start
        uout[slot] = b * NT + eidx;      // out row
        ulen[slot] = t - pz;             // length
      }
      if (mask) prev = c * 64 + (63 - __clzll((long long)mask));
      zc += __popcll(mask);
    }
    if (lane == 0){ nseg_b[b] = zc; counts_out[b] = (float)zc; }
  }
  __syncthreads();
  for (int i = tid; i <= 1024; i += 1024) hist[i] = 0;
  __syncthreads();
  for (int s = tid; s < NB * NT; s += 1024){
    int b = s >> 10, j = s & 1023;
    if (j < nseg_b[b]) atomicAdd(&hist[ulen[s]], 1);
  }
  __syncthreads();
  // cnt_ge[L] = #segments with len >= L  (L in 0..1025)
  for (int L = tid; L <= 1025; L += 1024){
    int sum = 0;
    int lo = (L < 1) ? 1 : L;
    for (int l = lo; l <= 1024; ++l) sum += hist[l];
    cnt_ge[L] = sum;
  }
  __syncthreads();
  for (int L = tid; L <= 1024; L += 1024) offs[L] = cnt_ge[L + 1]; // descending sort base
  __syncthreads();
  for (int s = tid; s < NB * NT; s += 1024){
    int b = s >> 10, j = s & 1023;
    if (j < nseg_b[b]){
      int len = ulen[s];
      int p = atomicAdd(&offs[len], 1);
      sgi[p] = ugi[s]; sout[p] = uout[s]; slen[p] = len;
    }
  }
}

// ---------------- K3: Gi = x @ W_ih^T + b_ih (bf16 MFMA, fp32 out) ----------------
__global__ __launch_bounds__(256) void k_gi_gemm(const float* __restrict__ x,
    const unsigned short* __restrict__ wih_b, const float* __restrict__ b_ih,
    float* __restrict__ gi_f, unsigned short* __restrict__ gi_b, int gi_is_f32){
  __shared__ unsigned short Alds[128 * 64];
  __shared__ unsigned short Blds[128 * 64];
  int tid = threadIdx.x;
  int wave = tid >> 6, lane = tid & 63;
  int ntile = blockIdx.x % 24, mtile = blockIdx.x / 24;
  int m0 = mtile * 128, n0 = ntile * 128;
  int mh = (wave >> 1) * 64, nh = (wave & 1) * 64;
  f32x4 acc[4][4];
#pragma unroll
  for (int i = 0; i < 4; ++i)
#pragma unroll
    for (int j = 0; j < 4; ++j) acc[i][j] = (f32x4){0.f, 0.f, 0.f, 0.f};

  for (int kc = 0; kc < 16; ++kc){
    __syncthreads();
    // stage A: 128x64 fp32 -> bf16
#pragma unroll
    for (int p = 0; p < 4; ++p){
      int e = (p * 256 + tid) * 8;
      int r = e >> 6, c = e & 63;
      const float* src = x + (size_t)(m0 + r) * ND + kc * 64 + c;
      float4 f0 = *(const float4*)src;
      float4 f1 = *(const float4*)(src + 4);
      u16x8 u;
      u[0]=f2b(f0.x); u[1]=f2b(f0.y); u[2]=f2b(f0.z); u[3]=f2b(f0.w);
      u[4]=f2b(f1.x); u[5]=f2b(f1.y); u[6]=f2b(f1.z); u[7]=f2b(f1.w);
      *(u16x8*)&Alds[r * 64 + c] = u;
    }
    // stage B: 128x64 bf16
#pragma unroll
    for (int p = 0; p < 4; ++p){
      int e = (p * 256 + tid) * 8;
      int r = e >> 6, c = e & 63;
      *(u16x8*)&Blds[r * 64 + c] = *(const u16x8*)(wih_b + (size_t)(n0 + r) * ND + kc * 64 + c);
    }
    __syncthreads();
#pragma unroll
    for (int ks = 0; ks < 2; ++ks){
      bf16x8 a[4], bb[4];
#pragma unroll
      for (int mi = 0; mi < 4; ++mi)
        a[mi] = *(const bf16x8*)&Alds[(mh + mi * 16 + (lane & 15)) * 64 + ks * 32 + (lane >> 4) * 8];
#pragma unroll
      for (int ni = 0; ni < 4; ++ni)
        bb[ni] = *(const bf16x8*)&Blds[(nh + ni * 16 + (lane & 15)) * 64 + ks * 32 + (lane >> 4) * 8];
#pragma unroll
      for (int mi = 0; mi < 4; ++mi)
#pragma unroll
        for (int ni = 0; ni < 4; ++ni)
          acc[mi][ni] = __builtin_amdgcn_mfma_f32_16x16x32_bf16(a[mi], bb[ni], acc[mi][ni], 0, 0, 0);
    }
  }
  // epilogue: add bias, store
#pragma unroll
  for (int mi = 0; mi < 4; ++mi){
    int row = m0 + mh + mi * 16 + (lane >> 4) * 4;
#pragma unroll
    for (int ni = 0; ni < 4; ++ni){
      int col = n0 + nh + ni * 16 + (lane & 15);
      float bias = b_ih[col];
#pragma unroll
      for (int rr = 0; rr < 4; ++rr){
        float v = acc[mi][ni][rr] + bias;
        if (gi_is_f32) gi_f[(size_t)(row + rr) * G3 + col] = v;
        else           gi_b[(size_t)(row + rr) * G3 + col] = f2b(v);
      }
    }
  }
}

// ---------------- K4: cooperative recurrence over length-sorted segments ----------------
__global__ __launch_bounds__(256) void k_recur(
    const unsigned short* __restrict__ whh_b, const float* __restrict__ b_hh,
    const float* __restrict__ gi_f, const unsigned short* __restrict__ gi_b, int gi_is_f32,
    const int* __restrict__ sgi, const int* __restrict__ sout, const int* __restrict__ slen,
    const int* __restrict__ cnt_ge,
    unsigned short* __restrict__ hbuf, float* __restrict__ out){
  __shared__ unsigned short Alds[64 * 64];    // 8 KB
  __shared__ unsigned short Wlds[192 * 64];   // 24 KB
  cg::grid_group grid = cg::this_grid();
  int tid = threadIdx.x;
  int wave = tid >> 6, lane = tid & 63;
  int nsegs = cnt_ge[1];

  // ---- iteration 0: h=0 so gh=b_hh; pure elementwise ----
  {
    int total = nsegs * (NH / 8);
    for (int idx = blockIdx.x * 256 + tid; idx < total; idx += gridDim.x * 256){
      int i = idx >> 7;
      int c0 = (idx & 127) * 8;
      int gir = sgi[i];
      int len = slen[i];
      bool emit = (len == 1);
      float* orow = out + (size_t)sout[i] * NH;
      unsigned short* hrow = hbuf + (size_t)HROWS * NH + (size_t)i * NH;  // write buf1
#pragma unroll
      for (int j = 0; j < 8; ++j){
        int c = c0 + j;
        float gr, gz, gn;
        if (gi_is_f32){
          const float* g = gi_f + (size_t)gir * G3;
          gr = g[c]; gz = g[NH + c]; gn = g[2 * NH + c];
        } else {
          const unsigned short* g = gi_b + (size_t)gir * G3;
          gr = b2f(g[c]); gz = b2f(g[NH + c]); gn = b2f(g[2 * NH + c]);
        }
        float r = sigm(gr + b_hh[c]);
        float z = sigm(gz + b_hh[NH + c]);
        float n = tanh_(gn + r * b_hh[2 * NH + c]);
        float hn = (1.0f - z) * n;
        if (emit) orow[c] = hn;
        else      hrow[c] = f2b(hn);
      }
    }
  }
  grid.sync();

  // ---- iterations k>=1: batched GEMM over active prefix + fused gates ----
  for (int k = 1; k <= 1023; ++k){
    int Ak = cnt_ge[k + 1];
    if (Ak <= 0) break;
    int Mt = (Ak + 63) >> 6;
    int tiles = Mt * 16;
    const unsigned short* hread = hbuf + (size_t)(k & 1) * HROWS * NH;
    unsigned short* hwrite      = hbuf + (size_t)((k + 1) & 1) * HROWS * NH;

    for (int tile = blockIdx.x; tile < tiles; tile += gridDim.x){
      int m0 = (tile >> 4) * 64;
      int hc0 = (tile & 15) * 64;
      f32x4 acc[12];
#pragma unroll
      for (int f = 0; f < 12; ++f) acc[f] = (f32x4){0.f, 0.f, 0.f, 0.f};

      for (int kc = 0; kc < 16; ++kc){
        __syncthreads();
        // stage A (64x64 of h_state, bf16)
#pragma unroll
        for (int p = 0; p < 2; ++p){
          int e = (p * 256 + tid) * 8;
          int r = e >> 6, c = e & 63;
          *(u16x8*)&Alds[r * 64 + c] =
              *(const u16x8*)(hread + (size_t)(m0 + r) * NH + kc * 64 + c);
        }
        // stage W (192x64: rows = gate*64 + col-offset)
#pragma unroll
        for (int p = 0; p < 6; ++p){
          int e = (p * 256 + tid) * 8;
          int wr = e >> 6, c = e & 63;
          int n = (wr >> 6) * NH + hc0 + (wr & 63);
          *(u16x8*)&Wlds[wr * 64 + c] =
              *(const u16x8*)(whh_b + (size_t)n * NH + kc * 64 + c);
        }
        __syncthreads();
#pragma unroll
        for (int ks = 0; ks < 2; ++ks){
          bf16x8 a = *(const bf16x8*)&Alds[(wave * 16 + (lane & 15)) * 64 + ks * 32 + (lane >> 4) * 8];
#pragma unroll
          for (int f = 0; f < 12; ++f){
            bf16x8 bb = *(const bf16x8*)&Wlds[(f * 16 + (lane & 15)) * 64 + ks * 32 + (lane >> 4) * 8];
            acc[f] = __builtin_amdgcn_mfma_f32_16x16x32_bf16(a, bb, acc[f], 0, 0, 0);
          }
        }
      }
      // epilogue: gates + emit/update
      int rb = m0 + wave * 16 + (lane >> 4) * 4;
#pragma unroll
      for (int rr = 0; rr < 4; ++rr){
        int i = rb + rr;
        if (i >= Ak) continue;
        int gir = sgi[i] + k;
        int len = slen[i];
        bool emit = (len == k + 1);
#pragma unroll
        for (int cgi = 0; cgi < 4; ++cgi){
          int c = hc0 + cgi * 16 + (lane & 15);
          float gr, gz, gn;
          if (gi_is_f32){
            const float* g = gi_f + (size_t)gir * G3;
            gr = g[c]; gz = g[NH + c]; gn = g[2 * NH + c];
          } else {
            const unsigned short* g = gi_b + (size_t)gir * G3;
            gr = b2f(g[c]); gz = b2f(g[NH + c]); gn = b2f(g[2 * NH + c]);
          }
          float ghr = acc[cgi][rr]     + b_hh[c];
          float ghz = acc[4 + cgi][rr] + b_hh[NH + c];
          float ghn = acc[8 + cgi][rr] + b_hh[2 * NH + c];
          float h = b2f(hread[(size_t)i * NH + c]);
          float r = sigm(gr + ghr);
          float z = sigm(gz + ghz);
          float n = tanh_(gn + r * ghn);
          float hn = (1.0f - z) * n + z * h;
          if (emit) out[(size_t)sout[i] * NH + c] = hn;
          else      hwrite[(size_t)i * NH + c] = f2b(hn);
        }
      }
    }
    grid.sync();
  }
}

extern "C" void kernel_launch(void* const* d_in, const int* in_sizes, int n_in,
                              void* d_out, int out_size, void* d_ws, size_t ws_size,
                              hipStream_t stream){
  (void)in_sizes; (void)n_in;
  const float* x   = (const float*)d_in[0];
  const float* wih = (const float*)d_in[1];
  const float* whh = (const float*)d_in[2];
  const float* bih = (const float*)d_in[3];
  const float* bhh = (const float*)d_in[4];
  const int*   seg = (const int*)d_in[5];
  float* outp = (float*)d_out;

  char* ws = (char*)d_ws;
  unsigned short* wih_b = (unsigned short*)(ws);
  unsigned short* whh_b = (unsigned short*)(ws + 6291456);
  size_t o_gi = 12582912;
  size_t gi_f_bytes = (size_t)MROWS * G3 * 4;
  size_t gi_b_bytes = (size_t)MROWS * G3 * 2;
  size_t desc_bytes = 1u << 20;
  size_t h_bytes = (size_t)2 * HROWS * NH * 2;
  int gi_is_f32 = (o_gi + gi_f_bytes + desc_bytes + h_bytes <= ws_size) ? 1 : 0;
  size_t o_desc = o_gi + (gi_is_f32 ? gi_f_bytes : gi_b_bytes);
  size_t o_h = o_desc + desc_bytes;

  float* gi_f = (float*)(ws + o_gi);
  unsigned short* gi_b = (unsigned short*)(ws + o_gi);
  int* ugi  = (int*)(ws + o_desc);
  int* uout = ugi + 32768;
  int* ulen = uout + 32768;
  int* sgi  = ulen + 32768;
  int* sout = sgi + 32768;
  int* slen = sout + 32768;
  int* nsegb = slen + 32768;
  int* cntge = nsegb + 32;
  unsigned short* hbuf = (unsigned short*)(ws + o_h);

  // zero output (non-emitted rows must be 0; also clears counts tail)
  hipMemsetAsync(d_out, 0, (size_t)out_size * 4, stream);

  k_convw<<<dim3(2048), dim3(256), 0, stream>>>(wih, whh, wih_b, whh_b, G3 * ND);

  float* counts_out = outp + (size_t)NB * NT * NH;
  k_segbuild<<<dim3(1), dim3(1024), 0, stream>>>(seg, ugi, uout, ulen, nsegb,
                                                 sgi, sout, slen, cntge, counts_out);

  k_gi_gemm<<<dim3(256 * 24), dim3(256), 0, stream>>>(x, wih_b, bih, gi_f, gi_b, gi_is_f32);

  const float* bhh_c = bhh;
  void* args[] = {
    (void*)&whh_b, (void*)&bhh_c, (void*)&gi_f, (void*)&gi_b, (void*)&gi_is_f32,
    (void*)&sgi, (void*)&sout, (void*)&slen, (void*)&cntge, (void*)&hbuf, (void*)&outp
  };
  hipLaunchCooperativeKernel((const void*)k_recur, dim3(512), dim3(256), args, 0, stream);
}

// Round 2
// 2121.596 us; speedup vs baseline: 1.2121x; 1.2121x over previous
//
#include <hip/hip_runtime.h>
#include <hip/hip_cooperative_groups.h>

namespace cg = cooperative_groups;

#define NB 32
#define NT 1024
#define ND 1024
#define NH 1024
#define G3 3072          // 3*NH
#define MROWS 32768      // NB*NT
#define HROWS 16512      // >= 16384 rows + pad

typedef __bf16 bf16x8 __attribute__((ext_vector_type(8)));
typedef float f32x4 __attribute__((ext_vector_type(4)));
typedef unsigned short u16x8 __attribute__((ext_vector_type(8)));
typedef unsigned short u16x4 __attribute__((ext_vector_type(4)));

__device__ __forceinline__ float b2f(unsigned short u){
  union { unsigned int i; float f; } v; v.i = ((unsigned int)u) << 16; return v.f;
}
__device__ __forceinline__ unsigned short f2b(float f){
  union { float f; unsigned int i; } v; v.f = f;
  unsigned int r = (v.i + 0x7FFFu + ((v.i >> 16) & 1u)) >> 16;
  return (unsigned short)r;
}
__device__ __forceinline__ float sigm(float x){ return 1.0f / (1.0f + __expf(-x)); }
__device__ __forceinline__ float tanh_(float x){ return 2.0f / (1.0f + __expf(-2.0f * x)) - 1.0f; }

// async global->LDS, 16B per lane; LDS dest = wave-uniform base + lane*16
__device__ __forceinline__ void g2l16(const void* g, void* l){
  __builtin_amdgcn_global_load_lds((__attribute__((address_space(1))) void*)g,
                                   (__attribute__((address_space(3))) void*)l, 16, 0, 0);
}

// ---------------- K1: fp32 -> bf16 conversions (weights + x) ----------------
__global__ __launch_bounds__(256) void k_conv(const float* __restrict__ wih,
    const float* __restrict__ whh, const float* __restrict__ x,
    unsigned short* __restrict__ wih_b, unsigned short* __restrict__ whh_b,
    unsigned short* __restrict__ x_b, int has_xb){
  int i0 = blockIdx.x * 256 + threadIdx.x;
  int stride = gridDim.x * 256;
  int nw4 = (G3 * ND) / 4;
  for (int j = i0; j < nw4; j += stride){
    float4 a = ((const float4*)wih)[j];
    float4 b = ((const float4*)whh)[j];
    u16x4 ua = {f2b(a.x), f2b(a.y), f2b(a.z), f2b(a.w)};
    u16x4 ub = {f2b(b.x), f2b(b.y), f2b(b.z), f2b(b.w)};
    ((u16x4*)wih_b)[j] = ua;
    ((u16x4*)whh_b)[j] = ub;
  }
  if (has_xb){
    int nx4 = (MROWS * ND) / 4;
    for (int j = i0; j < nx4; j += stride){
      float4 a = ((const float4*)x)[j];
      u16x4 u = {f2b(a.x), f2b(a.y), f2b(a.z), f2b(a.w)};
      ((u16x4*)x_b)[j] = u;
    }
  }
}

// ---------------- K2: segment build + counting sort (single block) ----------------
__global__ __launch_bounds__(1024) void k_segbuild(const int* __restrict__ seg,
    int* __restrict__ ugi, int* __restrict__ uout, int* __restrict__ ulen,
    int* __restrict__ nseg_b,
    int* __restrict__ sgi, int* __restrict__ sout, int* __restrict__ slen,
    int* __restrict__ cnt_ge, float* __restrict__ counts_out){
  __shared__ int hist[1025];
  __shared__ int offs[1025];
  int tid = threadIdx.x;
  int wave = tid >> 6, lane = tid & 63;

  for (int b = wave; b < NB; b += 16){
    int prev = -1;
    int zc = 0;
    for (int c = 0; c < 16; ++c){
      int t = c * 64 + lane;
      int v = seg[b * NT + t];
      unsigned long long mask = __ballot(v == 0);
      unsigned long long below = mask & ((1ULL << lane) - 1ULL);
      if (v == 0){
        int pz = below ? (c * 64 + (63 - __clzll((long long)below))) : prev;
        int eidx = zc + __popcll(below);
        int slot = b * NT + eidx;
        ugi[slot]  = b * NT + (pz + 1);
        uout[slot] = b * NT + eidx;
        ulen[slot] = t - pz;
      }
      if (mask) prev = c * 64 + (63 - __clzll((long long)mask));
      zc += __popcll(mask);
    }
    if (lane == 0){ nseg_b[b] = zc; counts_out[b] = (float)zc; }
  }
  __syncthreads();
  for (int i = tid; i <= 1024; i += 1024) hist[i] = 0;
  __syncthreads();
  for (int s = tid; s < NB * NT; s += 1024){
    int b = s >> 10, j = s & 1023;
    if (j < nseg_b[b]) atomicAdd(&hist[ulen[s]], 1);
  }
  __syncthreads();
  for (int L = tid; L <= 1025; L += 1024){
    int sum = 0;
    int lo = (L < 1) ? 1 : L;
    for (int l = lo; l <= 1024; ++l) sum += hist[l];
    cnt_ge[L] = sum;
  }
  __syncthreads();
  for (int L = tid; L <= 1024; L += 1024) offs[L] = cnt_ge[L + 1];
  __syncthreads();
  for (int s = tid; s < NB * NT; s += 1024){
    int b = s >> 10, j = s & 1023;
    if (j < nseg_b[b]){
      int len = ulen[s];
      int p = atomicAdd(&offs[len], 1);
      sgi[p] = ugi[s]; sout[p] = uout[s]; slen[p] = len;
    }
  }
}

// ---------------- K3: Gi = x @ W_ih^T + b_ih -> bf16 ----------------
// 128x128 tile, BK=64, global_load_lds(16B) staging, XOR-swizzled LDS.
__global__ __launch_bounds__(256, 2) void k_gi_gemm(const float* __restrict__ x,
    const unsigned short* __restrict__ x_b, const unsigned short* __restrict__ wih_b,
    const float* __restrict__ b_ih, unsigned short* __restrict__ gi_b, int use_xb){
  __shared__ unsigned short Alds[128 * 64];
  __shared__ unsigned short Blds[128 * 64];
  int tid = threadIdx.x;
  int w = tid >> 6, lane = tid & 63;
  int mtile = blockIdx.x / 24, ntile = blockIdx.x % 24;
  int m0 = mtile * 128, n0 = ntile * 128;
  int mh = (w >> 1) * 64, nh = (w & 1) * 64;
  int lrow = lane >> 3;                 // 0..7
  int lcol = 8 * ((lane & 7) ^ lrow);   // inverse-swizzled source col (elements)
  f32x4 acc[4][4];
#pragma unroll
  for (int i = 0; i < 4; ++i)
#pragma unroll
    for (int j = 0; j < 4; ++j) acc[i][j] = (f32x4){0.f, 0.f, 0.f, 0.f};

  for (int kc = 0; kc < 16; ++kc){
    __syncthreads();
    if (use_xb){
#pragma unroll
      for (int p = 0; p < 4; ++p){
        int s = w * 4 + p;              // 0..15, rows s*8..s*8+7
        g2l16(x_b + (size_t)(m0 + s * 8 + lrow) * ND + kc * 64 + lcol, &Alds[s * 512]);
      }
    } else {
#pragma unroll
      for (int p = 0; p < 4; ++p){
        int e = (p * 256 + tid) * 8;
        int r = e >> 6, c = e & 63;
        const float* src = x + (size_t)(m0 + r) * ND + kc * 64 + c;
        float4 f0 = *(const float4*)src;
        float4 f1 = *(const float4*)(src + 4);
        u16x8 u;
        u[0]=f2b(f0.x); u[1]=f2b(f0.y); u[2]=f2b(f0.z); u[3]=f2b(f0.w);
        u[4]=f2b(f1.x); u[5]=f2b(f1.y); u[6]=f2b(f1.z); u[7]=f2b(f1.w);
        *(u16x8*)&Alds[r * 64 + (c ^ ((r & 7) << 3))] = u;
      }
    }
#pragma unroll
    for (int p = 0; p < 4; ++p){
      int s = w * 4 + p;
      g2l16(wih_b + (size_t)(n0 + s * 8 + lrow) * ND + kc * 64 + lcol, &Blds[s * 512]);
    }
    __syncthreads();
#pragma unroll
    for (int ks = 0; ks < 2; ++ks){
      int co = ks * 32 + (lane >> 4) * 8;
      int cx = co ^ ((lane & 7) << 3);
      bf16x8 a[4], bb[4];
#pragma unroll
      for (int mi = 0; mi < 4; ++mi)
        a[mi] = *(const bf16x8*)&Alds[(mh + mi * 16 + (lane & 15)) * 64 + cx];
#pragma unroll
      for (int ni = 0; ni < 4; ++ni)
        bb[ni] = *(const bf16x8*)&Blds[(nh + ni * 16 + (lane & 15)) * 64 + cx];
#pragma unroll
      for (int mi = 0; mi < 4; ++mi)
#pragma unroll
        for (int ni = 0; ni < 4; ++ni)
          acc[mi][ni] = __builtin_amdgcn_mfma_f32_16x16x32_bf16(a[mi], bb[ni], acc[mi][ni], 0, 0, 0);
    }
  }
#pragma unroll
  for (int mi = 0; mi < 4; ++mi){
    int rbase = m0 + mh + mi * 16 + (lane >> 4) * 4;
#pragma unroll
    for (int ni = 0; ni < 4; ++ni){
      int col = n0 + nh + ni * 16 + (lane & 15);
      float bias = b_ih[col];
#pragma unroll
      for (int rr = 0; rr < 4; ++rr)
        gi_b[(size_t)(rbase + rr) * G3 + col] = f2b(acc[mi][ni][rr] + bias);
    }
  }
}

// ---------------- K4: cooperative recurrence ----------------
// per iteration k: GEMM  Gh[0:Ak, 3 gates x 64] tiles: M-tile 128, fused gate epilogue.
__global__ __launch_bounds__(256, 2) void k_recur(
    const unsigned short* __restrict__ whh_b, const float* __restrict__ b_hh,
    const unsigned short* __restrict__ gi_b,
    const int* __restrict__ sgi, const int* __restrict__ sout, const int* __restrict__ slen,
    const int* __restrict__ cnt_ge,
    unsigned short* __restrict__ hbuf, float* __restrict__ out){
  __shared__ unsigned short Alds[128 * 64];   // 16 KB
  __shared__ unsigned short Blds[192 * 64];   // 24 KB
  cg::grid_group grid = cg::this_grid();
  int tid = threadIdx.x;
  int w = tid >> 6, lane = tid & 63;
  int nseg = cnt_ge[1];

  // ---- iteration 0: h=0 => gh=b_hh; elementwise ----
  {
    int total = nseg * 128;  // 128 8-wide chunks per row
    for (int idx = blockIdx.x * 256 + tid; idx < total; idx += gridDim.x * 256){
      int i = idx >> 7;
      int c0 = (idx & 127) * 8;
      int gir = sgi[i];
      bool emit = (slen[i] == 1);
      const unsigned short* g = gi_b + (size_t)gir * G3;
      u16x8 vr = *(const u16x8*)(g + c0);
      u16x8 vz = *(const u16x8*)(g + NH + c0);
      u16x8 vn = *(const u16x8*)(g + 2 * NH + c0);
      float hn[8];
#pragma unroll
      for (int j = 0; j < 8; ++j){
        int c = c0 + j;
        float r = sigm(b2f(vr[j]) + b_hh[c]);
        float z = sigm(b2f(vz[j]) + b_hh[NH + c]);
        float n = tanh_(b2f(vn[j]) + r * b_hh[2 * NH + c]);
        hn[j] = (1.0f - z) * n;
      }
      if (emit){
        float* orow = out + (size_t)sout[i] * NH + c0;
        *(float4*)orow       = (float4){hn[0], hn[1], hn[2], hn[3]};
        *(float4*)(orow + 4) = (float4){hn[4], hn[5], hn[6], hn[7]};
      } else {
        u16x8 u;
#pragma unroll
        for (int j = 0; j < 8; ++j) u[j] = f2b(hn[j]);
        *(u16x8*)(hbuf + (size_t)HROWS * NH + (size_t)i * NH + c0) = u;
      }
    }
  }
  grid.sync();

  int lrow = lane >> 3;
  int lcol = 8 * ((lane & 7) ^ lrow);

  for (int k = 1; k <= 1023; ++k){
    int Ak = cnt_ge[k + 1];
    if (Ak <= 0) break;
    const unsigned short* hread = hbuf + (size_t)(k & 1) * HROWS * NH;
    unsigned short* hwrite      = hbuf + (size_t)((k + 1) & 1) * HROWS * NH;
    int Mt = (Ak + 127) >> 7;
    int tiles = Mt * 16;

    for (int tile = blockIdx.x; tile < tiles; tile += gridDim.x){
      int m0 = (tile >> 4) * 128;
      int nc0 = (tile & 15) * 64;     // col base within each gate
      f32x4 acc[2][12];
#pragma unroll
      for (int i = 0; i < 2; ++i)
#pragma unroll
        for (int f = 0; f < 12; ++f) acc[i][f] = (f32x4){0.f, 0.f, 0.f, 0.f};

      for (int kc = 0; kc < 16; ++kc){
        __syncthreads();
#pragma unroll
        for (int p = 0; p < 4; ++p){
          int s = w * 4 + p;            // 0..15
          g2l16(hread + (size_t)(m0 + s * 8 + lrow) * NH + kc * 64 + lcol, &Alds[s * 512]);
        }
#pragma unroll
        for (int p = 0; p < 6; ++p){
          int s = w * 6 + p;            // 0..23 ; gate = s>>3
          int wrow = (s >> 3) * NH + nc0 + (s & 7) * 8 + lrow;
          g2l16(whh_b + (size_t)wrow * NH + kc * 64 + lcol, &Blds[s * 512]);
        }
        __syncthreads();
#pragma unroll
        for (int ks = 0; ks < 2; ++ks){
          int co = ks * 32 + (lane >> 4) * 8;
          int cx = co ^ ((lane & 7) << 3);
          bf16x8 a0 = *(const bf16x8*)&Alds[(w * 32 + (lane & 15)) * 64 + cx];
          bf16x8 a1 = *(const bf16x8*)&Alds[(w * 32 + 16 + (lane & 15)) * 64 + cx];
#pragma unroll
          for (int f = 0; f < 12; ++f){
            bf16x8 bb = *(const bf16x8*)&Blds[(f * 16 + (lane & 15)) * 64 + cx];
            acc[0][f] = __builtin_amdgcn_mfma_f32_16x16x32_bf16(a0, bb, acc[0][f], 0, 0, 0);
            acc[1][f] = __builtin_amdgcn_mfma_f32_16x16x32_bf16(a1, bb, acc[1][f], 0, 0, 0);
          }
        }
      }
      // fused gate epilogue: rows = m0 + w*32 + mi*16 + (lane>>4)*4 + rr
      int rbase = m0 + w * 32 + (lane >> 4) * 4;
#pragma unroll
      for (int mi = 0; mi < 2; ++mi){
#pragma unroll
        for (int rr = 0; rr < 4; ++rr){
          int i = rbase + mi * 16 + rr;
          if (i >= Ak) continue;
          int gir = sgi[i] + k;
          bool emit = (slen[i] == k + 1);
          const unsigned short* g = gi_b + (size_t)gir * G3;
          const unsigned short* hr = hread + (size_t)i * NH;
          float* orow = out + (size_t)sout[i] * NH;
          unsigned short* hw = hwrite + (size_t)i * NH;
#pragma unroll
          for (int f = 0; f < 4; ++f){
            int c = nc0 + f * 16 + (lane & 15);
            float gr = b2f(g[c]);
            float gz = b2f(g[NH + c]);
            float gn = b2f(g[2 * NH + c]);
            float ghr = acc[mi][f][rr]     + b_hh[c];
            float ghz = acc[mi][4 + f][rr] + b_hh[NH + c];
            float ghn = acc[mi][8 + f][rr] + b_hh[2 * NH + c];
            float h = b2f(hr[c]);
            float r = sigm(gr + ghr);
            float z = sigm(gz + ghz);
            float n = tanh_(gn + r * ghn);
            float hn = (1.0f - z) * n + z * h;
            if (emit) orow[c] = hn;
            else      hw[c] = f2b(hn);
          }
        }
      }
    }
    grid.sync();
  }
}

extern "C" void kernel_launch(void* const* d_in, const int* in_sizes, int n_in,
                              void* d_out, int out_size, void* d_ws, size_t ws_size,
                              hipStream_t stream){
  (void)in_sizes; (void)n_in;
  const float* x   = (const float*)d_in[0];
  const float* wih = (const float*)d_in[1];
  const float* whh = (const float*)d_in[2];
  const float* bih = (const float*)d_in[3];
  const float* bhh = (const float*)d_in[4];
  const int*   seg = (const int*)d_in[5];
  float* outp = (float*)d_out;

  char* ws = (char*)d_ws;
  // layout (bytes):
  size_t o_wih = 0;                          // 6.0 MB
  size_t o_whh = 6291456;                    // 6.0 MB
  size_t o_gi  = 12582912;                   // gi_b bf16: 32768*3072*2 = 192 MB
  size_t o_desc = o_gi + (size_t)MROWS * G3 * 2;          // 1 MB
  size_t o_h    = o_desc + (1u << 20);                     // hbuf: 2*16512*1024*2 = 64.5 MB
  size_t o_xb   = o_h + (size_t)2 * HROWS * NH * 2;        // x_b: 64 MB
  size_t need_xb = o_xb + (size_t)MROWS * ND * 2;
  int has_xb = (ws_size >= need_xb) ? 1 : 0;

  unsigned short* wih_b = (unsigned short*)(ws + o_wih);
  unsigned short* whh_b = (unsigned short*)(ws + o_whh);
  unsigned short* gi_b  = (unsigned short*)(ws + o_gi);
  int* ugi  = (int*)(ws + o_desc);
  int* uout = ugi + 32768;
  int* ulen = uout + 32768;
  int* sgi  = ulen + 32768;
  int* sout = sgi + 32768;
  int* slen = sout + 32768;
  int* nsegb = slen + 32768;
  int* cntge = nsegb + 32;
  unsigned short* hbuf = (unsigned short*)(ws + o_h);
  unsigned short* x_b  = (unsigned short*)(ws + o_xb);

  hipMemsetAsync(d_out, 0, (size_t)out_size * 4, stream);

  k_conv<<<dim3(4096), dim3(256), 0, stream>>>(wih, whh, x, wih_b, whh_b, x_b, has_xb);

  float* counts_out = outp + (size_t)NB * NT * NH;
  k_segbuild<<<dim3(1), dim3(1024), 0, stream>>>(seg, ugi, uout, ulen, nsegb,
                                                 sgi, sout, slen, cntge, counts_out);

  k_gi_gemm<<<dim3(256 * 24), dim3(256), 0, stream>>>(x, x_b, wih_b, bih, gi_b, has_xb);

  const float* bhh_c = bhh;
  void* args[] = {
    (void*)&whh_b, (void*)&bhh_c, (void*)&gi_b,
    (void*)&sgi, (void*)&sout, (void*)&slen, (void*)&cntge, (void*)&hbuf, (void*)&outp
  };
  hipLaunchCooperativeKernel((const void*)k_recur, dim3(512), dim3(256), args, 0, stream);
}

// Round 3
// 1248.545 us; speedup vs baseline: 2.0597x; 1.6993x over previous
//
#include <hip/hip_runtime.h>
#include <hip/hip_cooperative_groups.h>

namespace cg = cooperative_groups;

#define NB 32
#define NT 1024
#define ND 1024
#define NH 1024
#define G3 3072          // 3*NH
#define MROWS 32768      // NB*NT
#define HROWS 16512      // >= 16384 rows + pad (Mt*128 <= 16512)

typedef __bf16 bf16x8 __attribute__((ext_vector_type(8)));
typedef float f32x4 __attribute__((ext_vector_type(4)));
typedef unsigned short u16x8 __attribute__((ext_vector_type(8)));
typedef unsigned short u16x4 __attribute__((ext_vector_type(4)));

__device__ __forceinline__ float b2f(unsigned short u){
  union { unsigned int i; float f; } v; v.i = ((unsigned int)u) << 16; return v.f;
}
__device__ __forceinline__ unsigned short f2b(float f){
  union { float f; unsigned int i; } v; v.f = f;
  unsigned int r = (v.i + 0x7FFFu + ((v.i >> 16) & 1u)) >> 16;
  return (unsigned short)r;
}
__device__ __forceinline__ float sigm(float x){ return 1.0f / (1.0f + __expf(-x)); }
__device__ __forceinline__ float tanh_(float x){ return 2.0f / (1.0f + __expf(-2.0f * x)) - 1.0f; }

// async global->LDS, 16B per lane; LDS dest = wave-uniform base + lane*16
__device__ __forceinline__ void g2l16(const void* g, void* l){
  __builtin_amdgcn_global_load_lds((__attribute__((address_space(1))) void*)g,
                                   (__attribute__((address_space(3))) void*)l, 16, 0, 0);
}

// ---------------- K1: fp32 -> bf16 conversions (weights + x) ----------------
__global__ __launch_bounds__(256) void k_conv(const float* __restrict__ wih,
    const float* __restrict__ whh, const float* __restrict__ x,
    unsigned short* __restrict__ wih_b, unsigned short* __restrict__ whh_b,
    unsigned short* __restrict__ x_b, int has_xb){
  int i0 = blockIdx.x * 256 + threadIdx.x;
  int stride = gridDim.x * 256;
  int nw4 = (G3 * ND) / 4;
  for (int j = i0; j < nw4; j += stride){
    float4 a = ((const float4*)wih)[j];
    float4 b = ((const float4*)whh)[j];
    u16x4 ua = {f2b(a.x), f2b(a.y), f2b(a.z), f2b(a.w)};
    u16x4 ub = {f2b(b.x), f2b(b.y), f2b(b.z), f2b(b.w)};
    ((u16x4*)wih_b)[j] = ua;
    ((u16x4*)whh_b)[j] = ub;
  }
  if (has_xb){
    int nx4 = (MROWS * ND) / 4;
    for (int j = i0; j < nx4; j += stride){
      float4 a = ((const float4*)x)[j];
      u16x4 u = {f2b(a.x), f2b(a.y), f2b(a.z), f2b(a.w)};
      ((u16x4*)x_b)[j] = u;
    }
  }
}

// ---------------- K2: segment build + counting sort (single block) ----------------
__global__ __launch_bounds__(1024) void k_segbuild(const int* __restrict__ seg,
    int* __restrict__ ugi, int* __restrict__ uout, int* __restrict__ ulen,
    int* __restrict__ nseg_b,
    int* __restrict__ sgi, int* __restrict__ sout, int* __restrict__ slen,
    int* __restrict__ cnt_ge, float* __restrict__ counts_out){
  __shared__ int hist[1025];
  __shared__ int offs[1025];
  int tid = threadIdx.x;
  int wave = tid >> 6, lane = tid & 63;

  for (int b = wave; b < NB; b += 16){
    int prev = -1;
    int zc = 0;
    for (int c = 0; c < 16; ++c){
      int t = c * 64 + lane;
      int v = seg[b * NT + t];
      unsigned long long mask = __ballot(v == 0);
      unsigned long long below = mask & ((1ULL << lane) - 1ULL);
      if (v == 0){
        int pz = below ? (c * 64 + (63 - __clzll((long long)below))) : prev;
        int eidx = zc + __popcll(below);
        int slot = b * NT + eidx;
        ugi[slot]  = b * NT + (pz + 1);
        uout[slot] = b * NT + eidx;
        ulen[slot] = t - pz;
      }
      if (mask) prev = c * 64 + (63 - __clzll((long long)mask));
      zc += __popcll(mask);
    }
    if (lane == 0){ nseg_b[b] = zc; counts_out[b] = (float)zc; }
  }
  __syncthreads();
  for (int i = tid; i <= 1024; i += 1024) hist[i] = 0;
  __syncthreads();
  for (int s = tid; s < NB * NT; s += 1024){
    int b = s >> 10, j = s & 1023;
    if (j < nseg_b[b]) atomicAdd(&hist[ulen[s]], 1);
  }
  __syncthreads();
  for (int L = tid; L <= 1025; L += 1024){
    int sum = 0;
    int lo = (L < 1) ? 1 : L;
    for (int l = lo; l <= 1024; ++l) sum += hist[l];
    cnt_ge[L] = sum;
  }
  __syncthreads();
  for (int L = tid; L <= 1024; L += 1024) offs[L] = cnt_ge[L + 1];
  __syncthreads();
  for (int s = tid; s < NB * NT; s += 1024){
    int b = s >> 10, j = s & 1023;
    if (j < nseg_b[b]){
      int len = ulen[s];
      int p = atomicAdd(&offs[len], 1);
      sgi[p] = ugi[s]; sout[p] = uout[s]; slen[p] = len;
    }
  }
}

// ---------------- K3: Gi = x @ W_ih^T + b_ih -> bf16 ----------------
__global__ __launch_bounds__(256, 2) void k_gi_gemm(const float* __restrict__ x,
    const unsigned short* __restrict__ x_b, const unsigned short* __restrict__ wih_b,
    const float* __restrict__ b_ih, unsigned short* __restrict__ gi_b, int use_xb){
  __shared__ unsigned short Alds[128 * 64];
  __shared__ unsigned short Blds[128 * 64];
  int tid = threadIdx.x;
  int w = tid >> 6, lane = tid & 63;
  int mtile = blockIdx.x / 24, ntile = blockIdx.x % 24;
  int m0 = mtile * 128, n0 = ntile * 128;
  int mh = (w >> 1) * 64, nh = (w & 1) * 64;
  int lrow = lane >> 3;
  int lcol = 8 * ((lane & 7) ^ lrow);
  f32x4 acc[4][4];
#pragma unroll
  for (int i = 0; i < 4; ++i)
#pragma unroll
    for (int j = 0; j < 4; ++j) acc[i][j] = (f32x4){0.f, 0.f, 0.f, 0.f};

  for (int kc = 0; kc < 16; ++kc){
    __syncthreads();
    if (use_xb){
#pragma unroll
      for (int p = 0; p < 4; ++p){
        int s = w * 4 + p;
        g2l16(x_b + (size_t)(m0 + s * 8 + lrow) * ND + kc * 64 + lcol, &Alds[s * 512]);
      }
    } else {
#pragma unroll
      for (int p = 0; p < 4; ++p){
        int e = (p * 256 + tid) * 8;
        int r = e >> 6, c = e & 63;
        const float* src = x + (size_t)(m0 + r) * ND + kc * 64 + c;
        float4 f0 = *(const float4*)src;
        float4 f1 = *(const float4*)(src + 4);
        u16x8 u;
        u[0]=f2b(f0.x); u[1]=f2b(f0.y); u[2]=f2b(f0.z); u[3]=f2b(f0.w);
        u[4]=f2b(f1.x); u[5]=f2b(f1.y); u[6]=f2b(f1.z); u[7]=f2b(f1.w);
        *(u16x8*)&Alds[r * 64 + (c ^ ((r & 7) << 3))] = u;
      }
    }
#pragma unroll
    for (int p = 0; p < 4; ++p){
      int s = w * 4 + p;
      g2l16(wih_b + (size_t)(n0 + s * 8 + lrow) * ND + kc * 64 + lcol, &Blds[s * 512]);
    }
    __syncthreads();
#pragma unroll
    for (int ks = 0; ks < 2; ++ks){
      int co = ks * 32 + (lane >> 4) * 8;
      int cx = co ^ ((lane & 7) << 3);
      bf16x8 a[4], bb[4];
#pragma unroll
      for (int mi = 0; mi < 4; ++mi)
        a[mi] = *(const bf16x8*)&Alds[(mh + mi * 16 + (lane & 15)) * 64 + cx];
#pragma unroll
      for (int ni = 0; ni < 4; ++ni)
        bb[ni] = *(const bf16x8*)&Blds[(nh + ni * 16 + (lane & 15)) * 64 + cx];
#pragma unroll
      for (int mi = 0; mi < 4; ++mi)
#pragma unroll
        for (int ni = 0; ni < 4; ++ni)
          acc[mi][ni] = __builtin_amdgcn_mfma_f32_16x16x32_bf16(a[mi], bb[ni], acc[mi][ni], 0, 0, 0);
    }
  }
#pragma unroll
  for (int mi = 0; mi < 4; ++mi){
    int rbase = m0 + mh + mi * 16 + (lane >> 4) * 4;
#pragma unroll
    for (int ni = 0; ni < 4; ++ni){
      int col = n0 + nh + ni * 16 + (lane & 15);
      float bias = b_ih[col];
#pragma unroll
      for (int rr = 0; rr < 4; ++rr)
        gi_b[(size_t)(rbase + rr) * G3 + col] = f2b(acc[mi][ni][rr] + bias);
    }
  }
}

// ---------------- step 0: h=0 => gh=b_hh; elementwise ----------------
__global__ __launch_bounds__(256) void k_step0(const float* __restrict__ b_hh,
    const unsigned short* __restrict__ gi_b,
    const int* __restrict__ sgi, const int* __restrict__ sout, const int* __restrict__ slen,
    const int* __restrict__ cnt_ge,
    unsigned short* __restrict__ hbuf, float* __restrict__ out){
  int nseg = cnt_ge[1];
  int total = nseg * 128;
  for (int idx = blockIdx.x * 256 + threadIdx.x; idx < total; idx += gridDim.x * 256){
    int i = idx >> 7;
    int c0 = (idx & 127) * 8;
    int gir = sgi[i];
    bool emit = (slen[i] == 1);
    const unsigned short* g = gi_b + (size_t)gir * G3;
    u16x8 vr = *(const u16x8*)(g + c0);
    u16x8 vz = *(const u16x8*)(g + NH + c0);
    u16x8 vn = *(const u16x8*)(g + 2 * NH + c0);
    float hn[8];
#pragma unroll
    for (int j = 0; j < 8; ++j){
      int c = c0 + j;
      float r = sigm(b2f(vr[j]) + b_hh[c]);
      float z = sigm(b2f(vz[j]) + b_hh[NH + c]);
      float n = tanh_(b2f(vn[j]) + r * b_hh[2 * NH + c]);
      hn[j] = (1.0f - z) * n;
    }
    if (emit){
      float* orow = out + (size_t)sout[i] * NH + c0;
      *(float4*)orow       = (float4){hn[0], hn[1], hn[2], hn[3]};
      *(float4*)(orow + 4) = (float4){hn[4], hn[5], hn[6], hn[7]};
    } else {
      u16x8 u;
#pragma unroll
      for (int j = 0; j < 8; ++j) u[j] = f2b(hn[j]);
      *(u16x8*)(hbuf + (size_t)HROWS * NH + (size_t)i * NH + c0) = u;
    }
  }
}

// ---------------- shared step-tile body (128 rows x [3 gates x 64 cols]) ----------------
__device__ __forceinline__ void step_tile(int k, int m0, int nc0, int Ak,
    const unsigned short* __restrict__ whh_b, const float* __restrict__ b_hh,
    const unsigned short* __restrict__ gi_b,
    const int* __restrict__ sgi, const int* __restrict__ sout, const int* __restrict__ slen,
    const unsigned short* __restrict__ hread, unsigned short* __restrict__ hwrite,
    float* __restrict__ out,
    unsigned short (*Alds)[128 * 64], unsigned short (*Blds)[192 * 64]){
  int tid = threadIdx.x;
  int w = tid >> 6, lane = tid & 63;
  int lrow = lane >> 3;
  int lcol = 8 * ((lane & 7) ^ lrow);
  f32x4 acc[2][12];
#pragma unroll
  for (int i = 0; i < 2; ++i)
#pragma unroll
    for (int f = 0; f < 12; ++f) acc[i][f] = (f32x4){0.f, 0.f, 0.f, 0.f};

#define STAGE(buf, kc) do {                                                        \
    _Pragma("unroll")                                                              \
    for (int p = 0; p < 4; ++p){                                                   \
      int s = w * 4 + p;                                                           \
      g2l16(hread + (size_t)(m0 + s * 8 + lrow) * NH + (kc) * 64 + lcol,           \
            &Alds[buf][s * 512]);                                                  \
    }                                                                              \
    _Pragma("unroll")                                                              \
    for (int p = 0; p < 6; ++p){                                                   \
      int s = w * 6 + p;                                                           \
      int wrow = (s >> 3) * NH + nc0 + (s & 7) * 8 + lrow;                         \
      g2l16(whh_b + (size_t)wrow * NH + (kc) * 64 + lcol, &Blds[buf][s * 512]);    \
    }                                                                              \
  } while (0)

  STAGE(0, 0);
  __syncthreads();           // drains vmcnt(0): buf0 ready
  int cur = 0;
  for (int kc = 0; kc < 16; ++kc){
    if (kc < 15) STAGE(cur ^ 1, kc + 1);   // issue next chunk, overlaps compute
#pragma unroll
    for (int ks = 0; ks < 2; ++ks){
      int co = ks * 32 + (lane >> 4) * 8;
      int cx = co ^ ((lane & 7) << 3);
      bf16x8 a0 = *(const bf16x8*)&Alds[cur][(w * 32 + (lane & 15)) * 64 + cx];
      bf16x8 a1 = *(const bf16x8*)&Alds[cur][(w * 32 + 16 + (lane & 15)) * 64 + cx];
#pragma unroll
      for (int f = 0; f < 12; ++f){
        bf16x8 bb = *(const bf16x8*)&Blds[cur][(f * 16 + (lane & 15)) * 64 + cx];
        acc[0][f] = __builtin_amdgcn_mfma_f32_16x16x32_bf16(a0, bb, acc[0][f], 0, 0, 0);
        acc[1][f] = __builtin_amdgcn_mfma_f32_16x16x32_bf16(a1, bb, acc[1][f], 0, 0, 0);
      }
    }
    __syncthreads();         // drains vmcnt(0) (next buf) + lgkm; protects WAR
    cur ^= 1;
  }
#undef STAGE

  // fused gate epilogue
  int rbase = m0 + w * 32 + (lane >> 4) * 4;
#pragma unroll
  for (int mi = 0; mi < 2; ++mi){
#pragma unroll
    for (int rr = 0; rr < 4; ++rr){
      int i = rbase + mi * 16 + rr;
      if (i >= Ak) continue;
      int gir = sgi[i] + k;
      bool emit = (slen[i] == k + 1);
      const unsigned short* g = gi_b + (size_t)gir * G3;
      const unsigned short* hr = hread + (size_t)i * NH;
      float* orow = out + (size_t)sout[i] * NH;
      unsigned short* hw = hwrite + (size_t)i * NH;
#pragma unroll
      for (int f = 0; f < 4; ++f){
        int c = nc0 + f * 16 + (lane & 15);
        float gr = b2f(g[c]);
        float gz = b2f(g[NH + c]);
        float gn = b2f(g[2 * NH + c]);
        float ghr = acc[mi][f][rr]     + b_hh[c];
        float ghz = acc[mi][4 + f][rr] + b_hh[NH + c];
        float ghn = acc[mi][8 + f][rr] + b_hh[2 * NH + c];
        float h = b2f(hr[c]);
        float r = sigm(gr + ghr);
        float z = sigm(gz + ghz);
        float n = tanh_(gn + r * ghn);
        float hn = (1.0f - z) * n + z * h;
        if (emit) orow[c] = hn;
        else      hw[c] = f2b(hn);
      }
    }
  }
}

// ---------------- per-step regular kernel (k = 1..24) ----------------
__global__ __launch_bounds__(256, 2) void k_step(int k,
    const unsigned short* __restrict__ whh_b, const float* __restrict__ b_hh,
    const unsigned short* __restrict__ gi_b,
    const int* __restrict__ sgi, const int* __restrict__ sout, const int* __restrict__ slen,
    const int* __restrict__ cnt_ge,
    unsigned short* __restrict__ hbuf, float* __restrict__ out){
  __shared__ unsigned short Alds[2][128 * 64];
  __shared__ unsigned short Blds[2][192 * 64];
  int Ak = cnt_ge[k + 1];
  if (Ak <= 0) return;
  int Mt = (Ak + 127) >> 7;
  int tiles = Mt * 16;
  const unsigned short* hread = hbuf + (size_t)(k & 1) * HROWS * NH;
  unsigned short* hwrite      = hbuf + (size_t)((k + 1) & 1) * HROWS * NH;
  int nwg = gridDim.x;
  int swz = (blockIdx.x & 7) * (nwg >> 3) + (blockIdx.x >> 3);  // XCD-contiguous chunks
  for (int t = swz; t < tiles; t += nwg){
    int cs = t / Mt, mt = t - cs * Mt;   // col-slice major: same W slice stays in XCD L2
    step_tile(k, mt * 128, cs * 64, Ak, whh_b, b_hh, gi_b, sgi, sout, slen,
              hread, hwrite, out, Alds, Blds);
  }
}

// ---------------- cooperative tail (k >= 25; no-op for this input) ----------------
__global__ __launch_bounds__(256, 2) void k_recur_tail(
    const unsigned short* __restrict__ whh_b, const float* __restrict__ b_hh,
    const unsigned short* __restrict__ gi_b,
    const int* __restrict__ sgi, const int* __restrict__ sout, const int* __restrict__ slen,
    const int* __restrict__ cnt_ge,
    unsigned short* __restrict__ hbuf, float* __restrict__ out){
  __shared__ unsigned short Alds[2][128 * 64];
  __shared__ unsigned short Blds[2][192 * 64];
  cg::grid_group grid = cg::this_grid();
  for (int k = 25; k <= 1023; ++k){
    int Ak = cnt_ge[k + 1];
    if (Ak <= 0) break;
    int Mt = (Ak + 127) >> 7;
    int tiles = Mt * 16;
    const unsigned short* hread = hbuf + (size_t)(k & 1) * HROWS * NH;
    unsigned short* hwrite      = hbuf + (size_t)((k + 1) & 1) * HROWS * NH;
    for (int t = blockIdx.x; t < tiles; t += gridDim.x){
      int cs = t / Mt, mt = t - cs * Mt;
      step_tile(k, mt * 128, cs * 64, Ak, whh_b, b_hh, gi_b, sgi, sout, slen,
                hread, hwrite, out, Alds, Blds);
    }
    grid.sync();
  }
}

extern "C" void kernel_launch(void* const* d_in, const int* in_sizes, int n_in,
                              void* d_out, int out_size, void* d_ws, size_t ws_size,
                              hipStream_t stream){
  (void)in_sizes; (void)n_in;
  const float* x   = (const float*)d_in[0];
  const float* wih = (const float*)d_in[1];
  const float* whh = (const float*)d_in[2];
  const float* bih = (const float*)d_in[3];
  const float* bhh = (const float*)d_in[4];
  const int*   seg = (const int*)d_in[5];
  float* outp = (float*)d_out;

  char* ws = (char*)d_ws;
  size_t o_wih = 0;                          // 6.0 MB
  size_t o_whh = 6291456;                    // 6.0 MB
  size_t o_gi  = 12582912;                   // gi_b bf16: 192 MB
  size_t o_desc = o_gi + (size_t)MROWS * G3 * 2;           // 1 MB
  size_t o_h    = o_desc + (1u << 20);                     // hbuf: 64.5 MB
  size_t o_xb   = o_h + (size_t)2 * HROWS * NH * 2;        // x_b: 64 MB
  size_t need_xb = o_xb + (size_t)MROWS * ND * 2;
  int has_xb = (ws_size >= need_xb) ? 1 : 0;

  unsigned short* wih_b = (unsigned short*)(ws + o_wih);
  unsigned short* whh_b = (unsigned short*)(ws + o_whh);
  unsigned short* gi_b  = (unsigned short*)(ws + o_gi);
  int* ugi  = (int*)(ws + o_desc);
  int* uout = ugi + 32768;
  int* ulen = uout + 32768;
  int* sgi  = ulen + 32768;
  int* sout = sgi + 32768;
  int* slen = sout + 32768;
  int* nsegb = slen + 32768;
  int* cntge = nsegb + 32;
  unsigned short* hbuf = (unsigned short*)(ws + o_h);
  unsigned short* x_b  = (unsigned short*)(ws + o_xb);

  hipMemsetAsync(d_out, 0, (size_t)out_size * 4, stream);

  k_conv<<<dim3(4096), dim3(256), 0, stream>>>(wih, whh, x, wih_b, whh_b, x_b, has_xb);

  float* counts_out = outp + (size_t)NB * NT * NH;
  k_segbuild<<<dim3(1), dim3(1024), 0, stream>>>(seg, ugi, uout, ulen, nsegb,
                                                 sgi, sout, slen, cntge, counts_out);

  k_gi_gemm<<<dim3(256 * 24), dim3(256), 0, stream>>>(x, x_b, wih_b, bih, gi_b, has_xb);

  k_step0<<<dim3(1024), dim3(256), 0, stream>>>(bhh, gi_b, sgi, sout, slen, cntge, hbuf, outp);

  // per-step regular launches; grid sized to expected Ak decay (grid-stride covers outliers)
  for (int k = 1; k <= 24; ++k){
    int g = (k == 1) ? 1024 : (k == 2) ? 512 : (k <= 4) ? 256 : 128;
    k_step<<<dim3(g), dim3(256), 0, stream>>>(k, whh_b, bhh, gi_b,
                                              sgi, sout, slen, cntge, hbuf, outp);
  }

  // cooperative tail for k >= 25 (worst-case correctness; no-op for this input)
  const unsigned short* whh_bc = whh_b;
  const float* bhh_c = bhh;
  const unsigned short* gi_bc = gi_b;
  const int *sgi_c = sgi, *sout_c = sout, *slen_c = slen, *cnt_c = cntge;
  void* targs[] = {
    (void*)&whh_bc, (void*)&bhh_c, (void*)&gi_bc,
    (void*)&sgi_c, (void*)&sout_c, (void*)&slen_c, (void*)&cnt_c,
    (void*)&hbuf, (void*)&outp
  };
  hipLaunchCooperativeKernel((const void*)k_recur_tail, dim3(512), dim3(256), targs, 0, stream);
}